// Round 16
// baseline (478.993 us; speedup 1.0000x reference)
//
#include <hip/hip_runtime.h>
#include <hip/hip_bf16.h>

// Problem constants (B,C,T,H,W = 2,128,4,32,32; L=6; N=T*H*W=4096)
#define BCNT 2
#define CCH  128
#define NTOK 4096
#define NLAY 6
// fp8 fold: per-operand scale = 0.125 * sqrt(log2(e)) so S_fp8 dot = S/64*log2e
#define QK8SCALE 0.15014030f

using f32x4   = __attribute__((ext_vector_type(4))) float;
using f32x16  = __attribute__((ext_vector_type(16))) float;
using bf16x8  = __attribute__((ext_vector_type(8))) short;
using i32x8   = __attribute__((ext_vector_type(8))) int;

static __device__ __forceinline__ ushort f2bf(float f) {
  unsigned u = __float_as_uint(f);
  u += 0x7FFF + ((u >> 16) & 1);   // RNE
  return (ushort)(u >> 16);
}
static __device__ __forceinline__ uint pk2(float lo, float hi) {
  uint r;
  asm volatile("v_cvt_pk_bf16_f32 %0, %1, %2" : "=v"(r) : "v"(lo), "v"(hi));
  return r;
}
static __device__ __forceinline__ uint pkf8(float a, float b) {
  uint r = 0;
  asm volatile("v_cvt_pk_fp8_f32 %0, %1, %2" : "+v"(r) : "v"(a), "v"(b));
  return r;
}
// v_permlane32_swap_b32: a.hi-lanes <-> b.lo-lanes
static __device__ __forceinline__ void plswap(uint& a, uint& b) {
  asm volatile("v_permlane32_swap_b32 %0, %1" : "+v"(a), "+v"(b));
}
static __device__ __forceinline__ float vexp2(float x) {
  float r;
  asm("v_exp_f32 %0, %1" : "=v"(r) : "v"(x));
  return r;
}
static __device__ __forceinline__ void dma16(const void* g, void* l) {
  __builtin_amdgcn_global_load_lds(
      (const __attribute__((address_space(1))) unsigned int*)g,
      (__attribute__((address_space(3))) unsigned int*)l, 16, 0, 0);
}
static __device__ __forceinline__ i32x8 cat8(uint4 a, uint4 b) {
  i32x8 r;
  r[0] = (int)a.x; r[1] = (int)a.y; r[2] = (int)a.z; r[3] = (int)a.w;
  r[4] = (int)b.x; r[5] = (int)b.y; r[6] = (int)b.z; r[7] = (int)b.w;
  return r;
}
// MX-scaled fp8 K=64 MFMA with unit scales (e8m0 127 = 1.0); fmt 0 = e4m3
static __device__ __forceinline__ f32x16 mxm(i32x8 a, i32x8 b, f32x16 c) {
  return __builtin_amdgcn_mfma_scale_f32_32x32x64_f8f6f4(a, b, c, 0, 0, 0, 127, 0, 127);
}

// ---------------------------------------------------------------------------
// x f32 [B][C][N] -> xT bf16 [B][N][C]
// ---------------------------------------------------------------------------
__global__ __launch_bounds__(256) void transpose_kernel(
    const float* __restrict__ x, ushort* __restrict__ xT)
{
  __shared__ ushort ls[64][68];
  const int t = threadIdx.x;
  const int ntile = blockIdx.x * 64, ctile = blockIdx.y * 64, b = blockIdx.z;
  const float* xb = x + ((size_t)b * CCH + ctile) * NTOK + ntile;
  #pragma unroll
  for (int p = 0; p < 4; ++p) {
    int idx = p * 256 + t;
    int cc = idx >> 4, n4 = (idx & 15) * 4;
    float4 v = *(const float4*)(xb + (size_t)cc * NTOK + n4);
    ls[cc][n4 + 0] = f2bf(v.x); ls[cc][n4 + 1] = f2bf(v.y);
    ls[cc][n4 + 2] = f2bf(v.z); ls[cc][n4 + 3] = f2bf(v.w);
  }
  __syncthreads();
  ushort* ob = xT + ((size_t)b * NTOK + ntile) * CCH + ctile;
  #pragma unroll
  for (int p = 0; p < 16; ++p) {
    int idx = p * 256 + t;
    int nn = idx >> 6, cc = idx & 63;
    ob[(size_t)nn * CCH + cc] = ls[cc][nn];
  }
}

// ---------------------------------------------------------------------------
// wcvt: W1/W2/Wg f32 -> Wb bf16 (once per launch). grid (96, 3).
// ---------------------------------------------------------------------------
__global__ __launch_bounds__(256) void wcvt_kernel(
    const float* __restrict__ W1, const float* __restrict__ W2,
    const float* __restrict__ Wg, ushort* __restrict__ Wb)
{
  const float* src = (blockIdx.y == 0) ? W1 : (blockIdx.y == 1) ? W2 : Wg;
  const size_t base = (size_t)blockIdx.y * NLAY * CCH * CCH;
  const size_t i = (size_t)blockIdx.x * 1024 + threadIdx.x * 4;
  float4 w = *(const float4*)(src + i);
  uint2 o = make_uint2(pk2(w.x, w.y), pk2(w.z, w.w));
  *(uint2*)(Wb + base + i) = o;
}

// ---------------------------------------------------------------------------
// qkv via MFMA, both tiles DMA-staged (row-XOR involution, linear dest).
// which=0: q8[n][o] fp8, 1: k8[n][o] fp8 (QK8SCALE folded), 2: vv[o][n] bf16.
// ---------------------------------------------------------------------------
__global__ __launch_bounds__(256) void qkv_kernel(
    const ushort* __restrict__ xT, const ushort* __restrict__ Wb,
    const float* __restrict__ b1, const float* __restrict__ b2,
    const float* __restrict__ bg,
    uchar* __restrict__ q8, uchar* __restrict__ k8, ushort* __restrict__ vv,
    int l0)
{
  __shared__ __align__(16) ushort as[128][128];
  __shared__ __align__(16) ushort bs[128][128];
  const int t = threadIdx.x;
  const int lane = t & 63, wave = t >> 6;
  const int ntile = blockIdx.x * 128;
  const int which = blockIdx.y;
  const int z = blockIdx.z;
  const int b = z & 1, lidx = z >> 1, layer = l0 + lidx;
  const float* bias = (which == 0 ? b1 : which == 1 ? b2 : bg)
                      + (size_t)layer * CCH;
  const ushort* W = Wb + ((size_t)which * NLAY + layer) * CCH * CCH;
  const ushort* xb = xT + ((size_t)b * NTOK + ntile) * CCH;
  const ushort* ga = (which < 2) ? xb : W;
  const ushort* gb = (which < 2) ? W : xb;

  #pragma unroll
  for (int j = 0; j < 8; ++j) {
    int row = wave * 32 + j * 4 + (lane >> 4);
    int qs = (lane & 15) ^ (row & 15);
    dma16(ga + (size_t)row * 128 + qs * 8, &as[wave * 32 + j * 4][0]);
    dma16(gb + (size_t)row * 128 + qs * 8, &bs[wave * 32 + j * 4][0]);
  }
  asm volatile("s_waitcnt vmcnt(0)" ::: "memory");
  __syncthreads();

  const int l16 = lane & 15, lg = lane >> 4;
  const int wr = (wave >> 1) * 64, wc = (wave & 1) * 64;

  f32x4 acc[4][4];
  #pragma unroll
  for (int i = 0; i < 4; ++i)
    #pragma unroll
    for (int j = 0; j < 4; ++j) acc[i][j] = (f32x4)0.f;

  #pragma unroll
  for (int kk = 0; kk < 4; ++kk) {
    bf16x8 a[4], bb[4];
    #pragma unroll
    for (int i = 0; i < 4; ++i) {
      int row = wr + i * 16 + l16;
      a[i] = *(const bf16x8*)&as[row][(((kk * 4 + lg) ^ (row & 15)) * 8)];
    }
    #pragma unroll
    for (int j = 0; j < 4; ++j) {
      int row = wc + j * 16 + l16;
      bb[j] = *(const bf16x8*)&bs[row][(((kk * 4 + lg) ^ (row & 15)) * 8)];
    }
    #pragma unroll
    for (int i = 0; i < 4; ++i)
      #pragma unroll
      for (int j = 0; j < 4; ++j)
        acc[i][j] = __builtin_amdgcn_mfma_f32_16x16x32_bf16(a[i], bb[j], acc[i][j], 0, 0, 0);
  }

  if (which < 2) {
    uchar* o8 = (which == 0 ? q8 : k8) + (size_t)z * NTOK * CCH;
    #pragma unroll
    for (int j = 0; j < 4; ++j) {
      float bv = bias[wc + j * 16 + l16];
      #pragma unroll
      for (int i = 0; i < 4; ++i)
        #pragma unroll
        for (int r = 0; r < 4; ++r) {
          int n = ntile + wr + i * 16 + lg * 4 + r;
          float val = (acc[i][j][r] + bv) * QK8SCALE;
          uint pb = pkf8(val, val);
          o8[(size_t)n * CCH + wc + j * 16 + l16] = (uchar)pb;
        }
    }
  } else {
    ushort* oz = vv + (size_t)z * NTOK * CCH;
    #pragma unroll
    for (int i = 0; i < 4; ++i)
      #pragma unroll
      for (int r = 0; r < 4; ++r) {
        int o = wr + i * 16 + lg * 4 + r;
        float bv = bias[o];
        #pragma unroll
        for (int j = 0; j < 4; ++j)
          oz[(size_t)o * NTOK + ntile + wc + j * 16 + l16] = f2bf(acc[i][j][r] + bv);
      }
  }
}

// ---------------------------------------------------------------------------
// dsum: D[z][m] += sum_n 2^(S'[n][m]) via MX K=64 fp8 MFMA (unit scales).
// ---------------------------------------------------------------------------
__global__ __launch_bounds__(256, 3) void dsum_kernel(
    const uchar* __restrict__ q8, const uchar* __restrict__ k8,
    float* __restrict__ D)
{
  __shared__ __align__(16) uchar ks[3][32][256];
  const int t = threadIdx.x;
  const int lane = t & 63, wave = t >> 6;
  const int l31 = lane & 31, hi = lane >> 5;

  const int bid = blockIdx.x, ngrid = gridDim.x;
  const int wg = (bid & 7) * (ngrid >> 3) + (bid >> 3);   // XCD swizzle
  const int z = wg >> 6, rem = wg & 63;
  const int nbase = (rem >> 3) * 512 + wave * 128;
  const int mstart = (rem & 7) * 512;

  const uchar* qz = q8 + (size_t)z * NTOK * CCH;
  const uchar* kz = k8 + (size_t)z * NTOK * CCH;

  i32x8 qf[4][2];
  #pragma unroll
  for (int nb = 0; nb < 4; ++nb)
    #pragma unroll
    for (int kk = 0; kk < 2; ++kk)
      qf[nb][kk] = *(const i32x8*)(qz + (size_t)(nbase + nb * 32 + l31) * CCH
                                   + kk * 64 + hi * 32);

#define STAGEK(p, msub) do {                                                  \
    _Pragma("unroll")                                                         \
    for (int d_ = 0; d_ < 2; ++d_) {                                          \
      int R_ = wave * 8 + d_ * 4 + (lane >> 4);                               \
      int qs_ = (lane & 15) ^ (R_ & 15);                                      \
      dma16(kz + (size_t)((msub) + 2 * R_ + (qs_ >> 3)) * CCH + (qs_ & 7) * 16, \
            &ks[p][wave * 8 + d_ * 4][0]);                                    \
    }                                                                         \
  } while (0)

  STAGEK(0, mstart);
  STAGEK(1, mstart + 64);
  asm volatile("s_waitcnt vmcnt(2)" ::: "memory");
  __builtin_amdgcn_s_barrier();

  float* Dz = D + (size_t)z * NTOK;
  #pragma unroll
  for (int st = 0; st < 8; ++st) {
    if (st + 2 < 8) STAGEK((st + 2) % 3, mstart + (st + 2) * 64);
    const int cur = st % 3;

    #pragma unroll
    for (int mbi = 0; mbi < 2; ++mbi) {
      const int mb = mbi ^ (wave & 1);
      f32x16 ss[4];
      #pragma unroll
      for (int nb = 0; nb < 4; ++nb) ss[nb] = (f32x16)0.f;
      const int row = mb * 32 + l31;
      const int R = row >> 1;
      __builtin_amdgcn_s_setprio(1);
      #pragma unroll
      for (int kk = 0; kk < 2; ++kk) {
        int p0 = (((row & 1) << 3) | (kk * 4 + hi * 2)) ^ (R & 15);
        uint4 ka = *(const uint4*)&ks[cur][R][p0 * 16];
        uint4 kb = *(const uint4*)&ks[cur][R][(p0 ^ 1) * 16];
        i32x8 kf = cat8(ka, kb);
        #pragma unroll
        for (int nb = 0; nb < 4; ++nb)
          ss[nb] = mxm(qf[nb][kk], kf, ss[nb]);
      }
      __builtin_amdgcn_s_setprio(0);
      float s = 0.f;
      #pragma unroll
      for (int nb = 0; nb < 4; ++nb)
        #pragma unroll
        for (int r = 0; r < 16; ++r) s += vexp2(ss[nb][r]);
      s += __shfl_xor(s, 32);
      if (lane < 32)
        atomicAdd(&Dz[mstart + st * 64 + mb * 32 + l31], s);
    }
    if (st < 7) {
      asm volatile("s_waitcnt vmcnt(4)" ::: "memory");
      __builtin_amdgcn_s_barrier();
    }
  }
#undef STAGEK
}

// ---------------------------------------------------------------------------
// scalev: v[z][c][m] *= 1/(D[z][m]*L)  (bf16 in-place, 8 elems/thread)
// ---------------------------------------------------------------------------
__global__ __launch_bounds__(256) void scalev_kernel(
    ushort* __restrict__ vv, const float* __restrict__ D)
{
  size_t i8 = ((size_t)blockIdx.x * 256 + threadIdx.x) * 8;
  int m = (int)(i8 & (NTOK - 1));
  int z = (int)(i8 >> 19);               // per-z elems = C*N = 2^19
  const float* dp = D + (size_t)z * NTOK + m;
  uint4 u = *(uint4*)(vv + i8);
  float4 d0 = *(const float4*)dp;
  float4 d1 = *(const float4*)(dp + 4);
  uint w[4] = {u.x, u.y, u.z, u.w};
  float ds[8] = {d0.x, d0.y, d0.z, d0.w, d1.x, d1.y, d1.z, d1.w};
  #pragma unroll
  for (int d = 0; d < 4; ++d) {
    float r0 = __builtin_amdgcn_rcpf(ds[2 * d] * (float)NLAY);
    float r1 = __builtin_amdgcn_rcpf(ds[2 * d + 1] * (float)NLAY);
    float lo = __uint_as_float(w[d] << 16) * r0;
    float hi = __uint_as_float(w[d] & 0xFFFF0000u) * r1;
    w[d] = pk2(lo, hi);
  }
  *(uint4*)(vv + i8) = make_uint4(w[0], w[1], w[2], w[3]);
}

// ---------------------------------------------------------------------------
// pv (layer-fused; MX K=64 S + bf16 PV; 2-BUFFER / 48KB LDS -> 3 blocks/CU):
// Per tau: wait own stage (vmcnt(6)) + barrier -> compute -> barrier ->
// issue stage(tau+2) into the buffer just freed. Per-wave work unchanged
// vs round 15; only co-residency (TLP) increases 2->3 blocks/CU.
// ---------------------------------------------------------------------------
template <int NL, bool PART>
__global__ __launch_bounds__(256, 3) void pv_kernel(
    const uchar* __restrict__ q8, const uchar* __restrict__ k8,
    const ushort* __restrict__ vv, float* __restrict__ accG,
    ushort* __restrict__ part)
{
  __shared__ __align__(16) uchar  ks[2][32][256];   // K fp8 row-paired
  __shared__ __align__(16) ushort vs[2][64][128];   // V bf16 row-paired
  const int t = threadIdx.x;
  const int lane = t & 63, wave = t >> 6;
  const int l31 = lane & 31, hi = lane >> 5;
  const size_t PLZ = (size_t)NTOK * CCH;

  const int bid = blockIdx.x, ngrid = gridDim.x;
  const int wg = (bid & 7) * (ngrid >> 3) + (bid >> 3);   // XCD swizzle
  const int b = wg >> 8, rem = wg & 255;
  const int ng = rem & 15, ms = rem >> 4;   // ng low: window-siblings co-XCD
  const int nbase = ng * 256 + wave * 64;
  const int mstart = ms * 256;              // 4 subtiles of 64 per layer

  i32x8 qf[2][2];                            // 32B/lane Q chunks (K=64 A-frag)
  f32x16 oacc[2][4];
  #pragma unroll
  for (int nb = 0; nb < 2; ++nb)
    #pragma unroll
    for (int cb = 0; cb < 4; ++cb) oacc[nb][cb] = (f32x16)0.f;

#define LOADQ(lidx) do {                                                      \
    const uchar* qz_ = q8 + (size_t)((lidx) * 2 + b) * PLZ;                   \
    _Pragma("unroll")                                                         \
    for (int nb_ = 0; nb_ < 2; ++nb_)                                         \
      _Pragma("unroll")                                                       \
      for (int kk_ = 0; kk_ < 2; ++kk_)                                       \
        qf[nb_][kk_] = *(const i32x8*)(qz_ + (size_t)(nbase + nb_ * 32 + l31) * CCH \
                                       + kk_ * 64 + hi * 32);                 \
  } while (0)

#define STAGE(p, tau) do {                                                    \
    const uchar*  kz_ = k8 + (size_t)(((tau) >> 2) * 2 + b) * PLZ;            \
    const ushort* vz_ = vv + (size_t)(((tau) >> 2) * 2 + b) * PLZ;            \
    const int msub_ = mstart + ((tau) & 3) * 64;                              \
    _Pragma("unroll")                                                         \
    for (int d_ = 0; d_ < 2; ++d_) {                                          \
      int R_ = wave * 8 + d_ * 4 + (lane >> 4);                               \
      int qs_ = (lane & 15) ^ (R_ & 15);                                      \
      dma16(kz_ + (size_t)(msub_ + 2 * R_ + (qs_ >> 3)) * CCH + (qs_ & 7) * 16, \
            &ks[p][wave * 8 + d_ * 4][0]);                                    \
    }                                                                         \
    _Pragma("unroll")                                                         \
    for (int d_ = 0; d_ < 4; ++d_) {                                          \
      int r_ = wave * 16 + d_ * 4 + (lane >> 4);                              \
      int qs_ = (lane & 15) ^ (r_ & 15);                                      \
      dma16(vz_ + (size_t)(r_ + 64 * (qs_ >> 3)) * NTOK + msub_ + (qs_ & 7) * 8, \
            &vs[p][wave * 16 + d_ * 4][0]);                                   \
    }                                                                         \
  } while (0)

  STAGE(0, 0);
  STAGE(1, 1);

  #pragma unroll 4
  for (int tau = 0; tau < 4 * NL; ++tau) {
    // wait own stage(tau) (oldest 6); stage(tau+1)'s 6 stay in flight
    asm volatile("s_waitcnt vmcnt(6)" ::: "memory");
    __builtin_amdgcn_s_barrier();
    if ((tau & 3) == 0) LOADQ(tau >> 2);
    const int cur = tau & 1;

    #pragma unroll
    for (int mbi = 0; mbi < 2; ++mbi) {
      const int mb = mbi ^ (wave & 1);   // wave-staggered phase order
      // ---- S^T via MX K=64: lane holds S[m = mb*32+(r&3)+8(r>>2)+4hi][n]
      f32x16 ss[2];
      ss[0] = (f32x16)0.f; ss[1] = (f32x16)0.f;
      const int row = mb * 32 + l31;
      const int R = row >> 1;
      __builtin_amdgcn_s_setprio(1);
      #pragma unroll
      for (int kk = 0; kk < 2; ++kk) {
        int p0 = (((row & 1) << 3) | (kk * 4 + hi * 2)) ^ (R & 15);
        uint4 ka = *(const uint4*)&ks[cur][R][p0 * 16];
        uint4 kb = *(const uint4*)&ks[cur][R][(p0 ^ 1) * 16];
        i32x8 kf = cat8(ka, kb);
        ss[0] = mxm(kf, qf[0][kk], ss[0]);
        ss[1] = mxm(kf, qf[1][kk], ss[1]);
      }
      __builtin_amdgcn_s_setprio(0);

      // ---- 2^S + cvt_pk + permlane32_swap -> PV A-frags
      bf16x8 paL[2][2];
      #pragma unroll
      for (int nb = 0; nb < 2; ++nb) {
        #pragma unroll
        for (int s = 0; s < 2; ++s) {
          uint w0 = pk2(vexp2(ss[nb][8 * s + 0]), vexp2(ss[nb][8 * s + 1]));
          uint w1 = pk2(vexp2(ss[nb][8 * s + 2]), vexp2(ss[nb][8 * s + 3]));
          uint w2 = pk2(vexp2(ss[nb][8 * s + 4]), vexp2(ss[nb][8 * s + 5]));
          uint w3 = pk2(vexp2(ss[nb][8 * s + 6]), vexp2(ss[nb][8 * s + 7]));
          plswap(w0, w2);
          plswap(w1, w3);
          uint4 ui = make_uint4(w0, w1, w2, w3);
          paL[nb][s] = *(bf16x8*)&ui;
        }
      }

      // ---- PV: oacc[nb][cb] += P x V (k-steps 2mb, 2mb+1) — bf16
      __builtin_amdgcn_s_setprio(1);
      #pragma unroll
      for (int cb = 0; cb < 4; ++cb) {
        const int c = cb * 32 + l31;
        const int r = c & 63;
        #pragma unroll
        for (int s = 0; s < 2; ++s) {
          int qs = ((c >> 6) << 3) | (4 * mb + 2 * s + hi);
          bf16x8 vf = *(const bf16x8*)&vs[cur][r][(qs ^ (r & 15)) * 8];
          oacc[0][cb] = __builtin_amdgcn_mfma_f32_32x32x16_bf16(paL[0][s], vf, oacc[0][cb], 0, 0, 0);
          oacc[1][cb] = __builtin_amdgcn_mfma_f32_32x32x16_bf16(paL[1][s], vf, oacc[1][cb], 0, 0, 0);
        }
      }
      __builtin_amdgcn_s_setprio(0);
    }

    // all waves done reading buf[cur] before refilling it
    __builtin_amdgcn_s_barrier();
    if (tau + 2 < 4 * NL) STAGE(cur, tau + 2);
  }
#undef STAGE
#undef LOADQ

  if (PART) {
    ushort* pz = part + (size_t)(ms * BCNT + b) * NTOK * CCH;
    #pragma unroll
    for (int nb = 0; nb < 2; ++nb)
      #pragma unroll
      for (int cb = 0; cb < 4; ++cb)
        #pragma unroll
        for (int r = 0; r < 16; ++r) {
          int n = nbase + nb * 32 + (r & 3) + 8 * (r >> 2) + 4 * hi;
          pz[(size_t)n * CCH + cb * 32 + l31] = f2bf(oacc[nb][cb][r]);
        }
  } else {
    float* az = accG + (size_t)b * NTOK * CCH;
    #pragma unroll
    for (int nb = 0; nb < 2; ++nb)
      #pragma unroll
      for (int cb = 0; cb < 4; ++cb)
        #pragma unroll
        for (int r = 0; r < 16; ++r) {
          int n = nbase + nb * 32 + (r & 3) + 8 * (r >> 2) + 4 * hi;
          atomicAdd(&az[(size_t)n * CCH + cb * 32 + l31], oacc[nb][cb][r]);
        }
  }
}

// ---------------------------------------------------------------------------
// finalize (atomic path): out[b][c][n] = acc[b][n][c] + x[b][c][n]
// ---------------------------------------------------------------------------
__global__ __launch_bounds__(256) void finalize_kernel(
    const float* __restrict__ acc, const float* __restrict__ x,
    float* __restrict__ out)
{
  __shared__ float ts[64][65];
  const int t = threadIdx.x;
  const int ntile = blockIdx.x * 64, ctile = blockIdx.y * 64, b = blockIdx.z;
  const float* ab = acc + ((size_t)b * NTOK + ntile) * CCH + ctile;
  #pragma unroll
  for (int p = 0; p < 4; ++p) {
    int idx = p * 256 + t;
    int nn = idx >> 4, c4 = (idx & 15) * 4;
    float4 v = *(const float4*)(ab + (size_t)nn * CCH + c4);
    ts[nn][c4 + 0] = v.x; ts[nn][c4 + 1] = v.y;
    ts[nn][c4 + 2] = v.z; ts[nn][c4 + 3] = v.w;
  }
  __syncthreads();
  const size_t base = ((size_t)b * CCH + ctile) * NTOK + ntile;
  #pragma unroll
  for (int p = 0; p < 16; ++p) {
    int idx = p * 256 + t;
    int nn = idx & 63, cc = idx >> 6;
    size_t o = base + (size_t)cc * NTOK + nn;
    out[o] = ts[nn][cc] + x[o];
  }
}

// ---------------------------------------------------------------------------
// finalize (partial path): out[b][c][n] = sum_ms part[ms][b][n][c] + x
// ---------------------------------------------------------------------------
__global__ __launch_bounds__(256) void finalize_part_kernel(
    const ushort* __restrict__ part, const float* __restrict__ x,
    float* __restrict__ out)
{
  __shared__ float ts[64][65];
  const int t = threadIdx.x;
  const int ntile = blockIdx.x * 64, ctile = blockIdx.y * 64, b = blockIdx.z;
  #pragma unroll
  for (int p = 0; p < 4; ++p) {
    int idx = p * 256 + t;
    int nn = idx >> 4, c4 = (idx & 15) * 4;
    float s0 = 0.f, s1 = 0.f, s2 = 0.f, s3 = 0.f;
    const ushort* pp = part + ((size_t)b * NTOK + ntile + nn) * CCH + ctile + c4;
    #pragma unroll
    for (int msi = 0; msi < 16; ++msi) {
      uint2 u = *(const uint2*)(pp + (size_t)msi * BCNT * NTOK * CCH);
      s0 += __uint_as_float(u.x << 16);
      s1 += __uint_as_float(u.x & 0xFFFF0000u);
      s2 += __uint_as_float(u.y << 16);
      s3 += __uint_as_float(u.y & 0xFFFF0000u);
    }
    ts[nn][c4 + 0] = s0; ts[nn][c4 + 1] = s1;
    ts[nn][c4 + 2] = s2; ts[nn][c4 + 3] = s3;
  }
  __syncthreads();
  const size_t base = ((size_t)b * CCH + ctile) * NTOK + ntile;
  #pragma unroll
  for (int p = 0; p < 16; ++p) {
    int idx = p * 256 + t;
    int nn = idx & 63, cc = idx >> 6;
    size_t o = base + (size_t)cc * NTOK + nn;
    out[o] = ts[nn][cc] + x[o];
  }
}

// ---------------------------------------------------------------------------
extern "C" void kernel_launch(void* const* d_in, const int* in_sizes, int n_in,
                              void* d_out, int out_size, void* d_ws, size_t ws_size,
                              hipStream_t stream)
{
  const float* x  = (const float*)d_in[0];
  const float* W1 = (const float*)d_in[1];
  const float* b1 = (const float*)d_in[2];
  const float* W2 = (const float*)d_in[3];
  const float* b2 = (const float*)d_in[4];
  const float* Wg = (const float*)d_in[5];
  const float* bg = (const float*)d_in[6];
  float* out = (float*)d_out;

  const size_t PL = (size_t)BCNT * NTOK * CCH;   // 1,048,576 elements per z-pair slab
  const size_t DSZ = (size_t)BCNT * NTOK;        // 8192
  const size_t WBSZ = (size_t)3 * NLAY * CCH * CCH;

  // need(nb) = xT + nb*(vv + q8 + k8) + Wb + nb*D + acc [+ part]
  int nb = 1;
  for (int cand : {6, 3, 2}) {
    size_t need = PL * 2 + (size_t)cand * (PL * 2 + PL + PL) + WBSZ * 2
                + (size_t)cand * DSZ * 4 + PL * 4;
    if (ws_size >= need) { nb = cand; break; }
  }
  size_t need_base = PL * 2 + (size_t)nb * (PL * 2 + PL + PL) + WBSZ * 2
                   + (size_t)nb * DSZ * 4 + PL * 4;
  bool usePart = (nb == 6) && (ws_size >= need_base + 16 * PL * 2);

  char* p = (char*)d_ws;
  ushort* xT = (ushort*)p; p += PL * 2;
  ushort* vv = (ushort*)p; p += (size_t)nb * PL * 2;
  uchar*  q8 = (uchar*)p;  p += (size_t)nb * PL;
  uchar*  k8 = (uchar*)p;  p += (size_t)nb * PL;
  ushort* Wb = (ushort*)p; p += WBSZ * 2;
  float*  D  = (float*)p;  p += (size_t)nb * DSZ * 4;
  float*  acc= (float*)p;  p += PL * 4;
  ushort* part = (ushort*)p;   // 16 * PL bf16 when usePart

  if (!usePart) hipMemsetAsync(acc, 0, PL * 4, stream);
  transpose_kernel<<<dim3(NTOK / 64, CCH / 64, BCNT), 256, 0, stream>>>(x, xT);
  wcvt_kernel<<<dim3(96, 3), 256, 0, stream>>>(W1, W2, Wg, Wb);

  for (int l0 = 0; l0 < NLAY; l0 += nb) {
    const int LB = nb * BCNT;
    hipMemsetAsync(D, 0, (size_t)LB * NTOK * 4, stream);
    qkv_kernel<<<dim3(NTOK / 128, 3, LB), 256, 0, stream>>>(
        xT, Wb, b1, b2, bg, q8, k8, vv, l0);
    dsum_kernel<<<dim3(LB * 64), 256, 0, stream>>>(q8, k8, D);
    scalev_kernel<<<dim3(LB * 256), 256, 0, stream>>>(vv, D);
    const dim3 pvg(BCNT * 256);
    if (usePart) {
      pv_kernel<6, true><<<pvg, 256, 0, stream>>>(q8, k8, vv, acc, part);
    } else {
      switch (nb) {
        case 6: pv_kernel<6, false><<<pvg, 256, 0, stream>>>(q8, k8, vv, acc, part); break;
        case 3: pv_kernel<3, false><<<pvg, 256, 0, stream>>>(q8, k8, vv, acc, part); break;
        case 2: pv_kernel<2, false><<<pvg, 256, 0, stream>>>(q8, k8, vv, acc, part); break;
        default: pv_kernel<1, false><<<pvg, 256, 0, stream>>>(q8, k8, vv, acc, part); break;
      }
    }
  }
  if (usePart)
    finalize_part_kernel<<<dim3(NTOK / 64, CCH / 64, BCNT), 256, 0, stream>>>(part, x, out);
  else
    finalize_kernel<<<dim3(NTOK / 64, CCH / 64, BCNT), 256, 0, stream>>>(acc, x, out);
}

// Round 17
// 144.385 us; speedup vs baseline: 3.3175x; 3.3175x over previous
//
#include <hip/hip_runtime.h>
#include <hip/hip_bf16.h>

// Problem constants (B,C,T,H,W = 2,128,4,32,32; L=6; N=T*H*W=4096)
#define BCNT 2
#define CCH  128
#define NTOK 4096
#define NLAY 6
// fp8 fold: per-operand scale = 0.125 * sqrt(log2(e)) so S_fp8 dot = S/64*log2e
#define QK8SCALE 0.15014030f

using f32x4   = __attribute__((ext_vector_type(4))) float;
using f32x16  = __attribute__((ext_vector_type(16))) float;
using bf16x8  = __attribute__((ext_vector_type(8))) short;
using i32x8   = __attribute__((ext_vector_type(8))) int;

static __device__ __forceinline__ ushort f2bf(float f) {
  unsigned u = __float_as_uint(f);
  u += 0x7FFF + ((u >> 16) & 1);   // RNE
  return (ushort)(u >> 16);
}
static __device__ __forceinline__ uint pk2(float lo, float hi) {
  uint r;
  asm volatile("v_cvt_pk_bf16_f32 %0, %1, %2" : "=v"(r) : "v"(lo), "v"(hi));
  return r;
}
static __device__ __forceinline__ uint pkf8(float a, float b) {
  uint r = 0;
  asm volatile("v_cvt_pk_fp8_f32 %0, %1, %2" : "+v"(r) : "v"(a), "v"(b));
  return r;
}
// v_permlane32_swap_b32: a.hi-lanes <-> b.lo-lanes
static __device__ __forceinline__ void plswap(uint& a, uint& b) {
  asm volatile("v_permlane32_swap_b32 %0, %1" : "+v"(a), "+v"(b));
}
static __device__ __forceinline__ float vexp2(float x) {
  float r;
  asm("v_exp_f32 %0, %1" : "=v"(r) : "v"(x));
  return r;
}
static __device__ __forceinline__ void dma16(const void* g, void* l) {
  __builtin_amdgcn_global_load_lds(
      (const __attribute__((address_space(1))) unsigned int*)g,
      (__attribute__((address_space(3))) unsigned int*)l, 16, 0, 0);
}
static __device__ __forceinline__ i32x8 cat8(uint4 a, uint4 b) {
  i32x8 r;
  r[0] = (int)a.x; r[1] = (int)a.y; r[2] = (int)a.z; r[3] = (int)a.w;
  r[4] = (int)b.x; r[5] = (int)b.y; r[6] = (int)b.z; r[7] = (int)b.w;
  return r;
}
// MX-scaled fp8 K=64 MFMA with unit scales (e8m0 127 = 1.0); fmt 0 = e4m3
static __device__ __forceinline__ f32x16 mxm(i32x8 a, i32x8 b, f32x16 c) {
  return __builtin_amdgcn_mfma_scale_f32_32x32x64_f8f6f4(a, b, c, 0, 0, 0, 127, 0, 127);
}

// ---------------------------------------------------------------------------
// x f32 [B][C][N] -> xT bf16 [B][N][C]
// ---------------------------------------------------------------------------
__global__ __launch_bounds__(256) void transpose_kernel(
    const float* __restrict__ x, ushort* __restrict__ xT)
{
  __shared__ ushort ls[64][68];
  const int t = threadIdx.x;
  const int ntile = blockIdx.x * 64, ctile = blockIdx.y * 64, b = blockIdx.z;
  const float* xb = x + ((size_t)b * CCH + ctile) * NTOK + ntile;
  #pragma unroll
  for (int p = 0; p < 4; ++p) {
    int idx = p * 256 + t;
    int cc = idx >> 4, n4 = (idx & 15) * 4;
    float4 v = *(const float4*)(xb + (size_t)cc * NTOK + n4);
    ls[cc][n4 + 0] = f2bf(v.x); ls[cc][n4 + 1] = f2bf(v.y);
    ls[cc][n4 + 2] = f2bf(v.z); ls[cc][n4 + 3] = f2bf(v.w);
  }
  __syncthreads();
  ushort* ob = xT + ((size_t)b * NTOK + ntile) * CCH + ctile;
  #pragma unroll
  for (int p = 0; p < 16; ++p) {
    int idx = p * 256 + t;
    int nn = idx >> 6, cc = idx & 63;
    ob[(size_t)nn * CCH + cc] = ls[cc][nn];
  }
}

// ---------------------------------------------------------------------------
// wcvt: W1/W2/Wg f32 -> Wb bf16 (once per launch). grid (96, 3).
// ---------------------------------------------------------------------------
__global__ __launch_bounds__(256) void wcvt_kernel(
    const float* __restrict__ W1, const float* __restrict__ W2,
    const float* __restrict__ Wg, ushort* __restrict__ Wb)
{
  const float* src = (blockIdx.y == 0) ? W1 : (blockIdx.y == 1) ? W2 : Wg;
  const size_t base = (size_t)blockIdx.y * NLAY * CCH * CCH;
  const size_t i = (size_t)blockIdx.x * 1024 + threadIdx.x * 4;
  float4 w = *(const float4*)(src + i);
  uint2 o = make_uint2(pk2(w.x, w.y), pk2(w.z, w.w));
  *(uint2*)(Wb + base + i) = o;
}

// ---------------------------------------------------------------------------
// qkv via MFMA, both tiles DMA-staged (row-XOR involution, linear dest).
// which=0: q8[n][o] fp8, 1: k8[n][o] fp8 (QK8SCALE folded), 2: vv[o][n] bf16.
// ---------------------------------------------------------------------------
__global__ __launch_bounds__(256) void qkv_kernel(
    const ushort* __restrict__ xT, const ushort* __restrict__ Wb,
    const float* __restrict__ b1, const float* __restrict__ b2,
    const float* __restrict__ bg,
    uchar* __restrict__ q8, uchar* __restrict__ k8, ushort* __restrict__ vv,
    int l0)
{
  __shared__ __align__(16) ushort as[128][128];
  __shared__ __align__(16) ushort bs[128][128];
  const int t = threadIdx.x;
  const int lane = t & 63, wave = t >> 6;
  const int ntile = blockIdx.x * 128;
  const int which = blockIdx.y;
  const int z = blockIdx.z;
  const int b = z & 1, lidx = z >> 1, layer = l0 + lidx;
  const float* bias = (which == 0 ? b1 : which == 1 ? b2 : bg)
                      + (size_t)layer * CCH;
  const ushort* W = Wb + ((size_t)which * NLAY + layer) * CCH * CCH;
  const ushort* xb = xT + ((size_t)b * NTOK + ntile) * CCH;
  const ushort* ga = (which < 2) ? xb : W;
  const ushort* gb = (which < 2) ? W : xb;

  #pragma unroll
  for (int j = 0; j < 8; ++j) {
    int row = wave * 32 + j * 4 + (lane >> 4);
    int qs = (lane & 15) ^ (row & 15);
    dma16(ga + (size_t)row * 128 + qs * 8, &as[wave * 32 + j * 4][0]);
    dma16(gb + (size_t)row * 128 + qs * 8, &bs[wave * 32 + j * 4][0]);
  }
  asm volatile("s_waitcnt vmcnt(0)" ::: "memory");
  __syncthreads();

  const int l16 = lane & 15, lg = lane >> 4;
  const int wr = (wave >> 1) * 64, wc = (wave & 1) * 64;

  f32x4 acc[4][4];
  #pragma unroll
  for (int i = 0; i < 4; ++i)
    #pragma unroll
    for (int j = 0; j < 4; ++j) acc[i][j] = (f32x4)0.f;

  #pragma unroll
  for (int kk = 0; kk < 4; ++kk) {
    bf16x8 a[4], bb[4];
    #pragma unroll
    for (int i = 0; i < 4; ++i) {
      int row = wr + i * 16 + l16;
      a[i] = *(const bf16x8*)&as[row][(((kk * 4 + lg) ^ (row & 15)) * 8)];
    }
    #pragma unroll
    for (int j = 0; j < 4; ++j) {
      int row = wc + j * 16 + l16;
      bb[j] = *(const bf16x8*)&bs[row][(((kk * 4 + lg) ^ (row & 15)) * 8)];
    }
    #pragma unroll
    for (int i = 0; i < 4; ++i)
      #pragma unroll
      for (int j = 0; j < 4; ++j)
        acc[i][j] = __builtin_amdgcn_mfma_f32_16x16x32_bf16(a[i], bb[j], acc[i][j], 0, 0, 0);
  }

  if (which < 2) {
    uchar* o8 = (which == 0 ? q8 : k8) + (size_t)z * NTOK * CCH;
    #pragma unroll
    for (int j = 0; j < 4; ++j) {
      float bv = bias[wc + j * 16 + l16];
      #pragma unroll
      for (int i = 0; i < 4; ++i)
        #pragma unroll
        for (int r = 0; r < 4; ++r) {
          int n = ntile + wr + i * 16 + lg * 4 + r;
          float val = (acc[i][j][r] + bv) * QK8SCALE;
          uint pb = pkf8(val, val);
          o8[(size_t)n * CCH + wc + j * 16 + l16] = (uchar)pb;
        }
    }
  } else {
    ushort* oz = vv + (size_t)z * NTOK * CCH;
    #pragma unroll
    for (int i = 0; i < 4; ++i)
      #pragma unroll
      for (int r = 0; r < 4; ++r) {
        int o = wr + i * 16 + lg * 4 + r;
        float bv = bias[o];
        #pragma unroll
        for (int j = 0; j < 4; ++j)
          oz[(size_t)o * NTOK + ntile + wc + j * 16 + l16] = f2bf(acc[i][j][r] + bv);
      }
  }
}

// ---------------------------------------------------------------------------
// dsum: D[z][m] += sum_n 2^(S'[n][m]) via MX K=64 fp8 MFMA (unit scales).
// ---------------------------------------------------------------------------
__global__ __launch_bounds__(256, 3) void dsum_kernel(
    const uchar* __restrict__ q8, const uchar* __restrict__ k8,
    float* __restrict__ D)
{
  __shared__ __align__(16) uchar ks[3][32][256];
  const int t = threadIdx.x;
  const int lane = t & 63, wave = t >> 6;
  const int l31 = lane & 31, hi = lane >> 5;

  const int bid = blockIdx.x, ngrid = gridDim.x;
  const int wg = (bid & 7) * (ngrid >> 3) + (bid >> 3);   // XCD swizzle
  const int z = wg >> 6, rem = wg & 63;
  const int nbase = (rem >> 3) * 512 + wave * 128;
  const int mstart = (rem & 7) * 512;

  const uchar* qz = q8 + (size_t)z * NTOK * CCH;
  const uchar* kz = k8 + (size_t)z * NTOK * CCH;

  i32x8 qf[4][2];
  #pragma unroll
  for (int nb = 0; nb < 4; ++nb)
    #pragma unroll
    for (int kk = 0; kk < 2; ++kk)
      qf[nb][kk] = *(const i32x8*)(qz + (size_t)(nbase + nb * 32 + l31) * CCH
                                   + kk * 64 + hi * 32);

#define STAGEK(p, msub) do {                                                  \
    _Pragma("unroll")                                                         \
    for (int d_ = 0; d_ < 2; ++d_) {                                          \
      int R_ = wave * 8 + d_ * 4 + (lane >> 4);                               \
      int qs_ = (lane & 15) ^ (R_ & 15);                                      \
      dma16(kz + (size_t)((msub) + 2 * R_ + (qs_ >> 3)) * CCH + (qs_ & 7) * 16, \
            &ks[p][wave * 8 + d_ * 4][0]);                                    \
    }                                                                         \
  } while (0)

  STAGEK(0, mstart);
  STAGEK(1, mstart + 64);
  asm volatile("s_waitcnt vmcnt(2)" ::: "memory");
  __builtin_amdgcn_s_barrier();

  float* Dz = D + (size_t)z * NTOK;
  #pragma unroll
  for (int st = 0; st < 8; ++st) {
    if (st + 2 < 8) STAGEK((st + 2) % 3, mstart + (st + 2) * 64);
    const int cur = st % 3;

    #pragma unroll
    for (int mbi = 0; mbi < 2; ++mbi) {
      const int mb = mbi ^ (wave & 1);
      f32x16 ss[4];
      #pragma unroll
      for (int nb = 0; nb < 4; ++nb) ss[nb] = (f32x16)0.f;
      const int row = mb * 32 + l31;
      const int R = row >> 1;
      __builtin_amdgcn_s_setprio(1);
      #pragma unroll
      for (int kk = 0; kk < 2; ++kk) {
        int p0 = (((row & 1) << 3) | (kk * 4 + hi * 2)) ^ (R & 15);
        uint4 ka = *(const uint4*)&ks[cur][R][p0 * 16];
        uint4 kb = *(const uint4*)&ks[cur][R][(p0 ^ 1) * 16];
        i32x8 kf = cat8(ka, kb);
        #pragma unroll
        for (int nb = 0; nb < 4; ++nb)
          ss[nb] = mxm(qf[nb][kk], kf, ss[nb]);
      }
      __builtin_amdgcn_s_setprio(0);
      float s = 0.f;
      #pragma unroll
      for (int nb = 0; nb < 4; ++nb)
        #pragma unroll
        for (int r = 0; r < 16; ++r) s += vexp2(ss[nb][r]);
      s += __shfl_xor(s, 32);
      if (lane < 32)
        atomicAdd(&Dz[mstart + st * 64 + mb * 32 + l31], s);
    }
    if (st < 7) {
      asm volatile("s_waitcnt vmcnt(4)" ::: "memory");
      __builtin_amdgcn_s_barrier();
    }
  }
#undef STAGEK
}

// ---------------------------------------------------------------------------
// scalev: v[z][c][m] *= 1/(D[z][m]*L)  (bf16 in-place, 8 elems/thread)
// ---------------------------------------------------------------------------
__global__ __launch_bounds__(256) void scalev_kernel(
    ushort* __restrict__ vv, const float* __restrict__ D)
{
  size_t i8 = ((size_t)blockIdx.x * 256 + threadIdx.x) * 8;
  int m = (int)(i8 & (NTOK - 1));
  int z = (int)(i8 >> 19);               // per-z elems = C*N = 2^19
  const float* dp = D + (size_t)z * NTOK + m;
  uint4 u = *(uint4*)(vv + i8);
  float4 d0 = *(const float4*)dp;
  float4 d1 = *(const float4*)(dp + 4);
  uint w[4] = {u.x, u.y, u.z, u.w};
  float ds[8] = {d0.x, d0.y, d0.z, d0.w, d1.x, d1.y, d1.z, d1.w};
  #pragma unroll
  for (int d = 0; d < 4; ++d) {
    float r0 = __builtin_amdgcn_rcpf(ds[2 * d] * (float)NLAY);
    float r1 = __builtin_amdgcn_rcpf(ds[2 * d + 1] * (float)NLAY);
    float lo = __uint_as_float(w[d] << 16) * r0;
    float hi = __uint_as_float(w[d] & 0xFFFF0000u) * r1;
    w[d] = pk2(lo, hi);
  }
  *(uint4*)(vv + i8) = make_uint4(w[0], w[1], w[2], w[3]);
}

// ---------------------------------------------------------------------------
// pv (layer-fused, 3-buffer counted pipeline; MX K=64 S + bf16 PV — the
// round-15 configuration, best measured, no spill):
//   out partials: PART ? plain bf16 stores to part[ms][b][n][c]
//                       : fp32 atomicAdd into acc[b][n][c]
// ---------------------------------------------------------------------------
template <int NL, bool PART>
__global__ __launch_bounds__(256, 2) void pv_kernel(
    const uchar* __restrict__ q8, const uchar* __restrict__ k8,
    const ushort* __restrict__ vv, float* __restrict__ accG,
    ushort* __restrict__ part)
{
  __shared__ __align__(16) uchar  ks[3][32][256];   // K fp8 row-paired
  __shared__ __align__(16) ushort vs[3][64][128];   // V bf16 row-paired
  const int t = threadIdx.x;
  const int lane = t & 63, wave = t >> 6;
  const int l31 = lane & 31, hi = lane >> 5;
  const size_t PLZ = (size_t)NTOK * CCH;

  const int bid = blockIdx.x, ngrid = gridDim.x;
  const int wg = (bid & 7) * (ngrid >> 3) + (bid >> 3);   // XCD swizzle
  const int b = wg >> 8, rem = wg & 255;
  const int ng = rem & 15, ms = rem >> 4;   // ng low: window-siblings co-XCD
  const int nbase = ng * 256 + wave * 64;
  const int mstart = ms * 256;              // 4 subtiles of 64 per layer

  i32x8 qf[2][2];                            // 32B/lane Q chunks (K=64 A-frag)
  f32x16 oacc[2][4];
  #pragma unroll
  for (int nb = 0; nb < 2; ++nb)
    #pragma unroll
    for (int cb = 0; cb < 4; ++cb) oacc[nb][cb] = (f32x16)0.f;

#define LOADQ(lidx) do {                                                      \
    const uchar* qz_ = q8 + (size_t)((lidx) * 2 + b) * PLZ;                   \
    _Pragma("unroll")                                                         \
    for (int nb_ = 0; nb_ < 2; ++nb_)                                         \
      _Pragma("unroll")                                                       \
      for (int kk_ = 0; kk_ < 2; ++kk_)                                       \
        qf[nb_][kk_] = *(const i32x8*)(qz_ + (size_t)(nbase + nb_ * 32 + l31) * CCH \
                                       + kk_ * 64 + hi * 32);                 \
  } while (0)

#define STAGE(p, tau) do {                                                    \
    const uchar*  kz_ = k8 + (size_t)(((tau) >> 2) * 2 + b) * PLZ;            \
    const ushort* vz_ = vv + (size_t)(((tau) >> 2) * 2 + b) * PLZ;            \
    const int msub_ = mstart + ((tau) & 3) * 64;                              \
    _Pragma("unroll")                                                         \
    for (int d_ = 0; d_ < 2; ++d_) {                                          \
      int R_ = wave * 8 + d_ * 4 + (lane >> 4);                               \
      int qs_ = (lane & 15) ^ (R_ & 15);                                      \
      dma16(kz_ + (size_t)(msub_ + 2 * R_ + (qs_ >> 3)) * CCH + (qs_ & 7) * 16, \
            &ks[p][wave * 8 + d_ * 4][0]);                                    \
    }                                                                         \
    _Pragma("unroll")                                                         \
    for (int d_ = 0; d_ < 4; ++d_) {                                          \
      int r_ = wave * 16 + d_ * 4 + (lane >> 4);                              \
      int qs_ = (lane & 15) ^ (r_ & 15);                                      \
      dma16(vz_ + (size_t)(r_ + 64 * (qs_ >> 3)) * NTOK + msub_ + (qs_ & 7) * 8, \
            &vs[p][wave * 16 + d_ * 4][0]);                                   \
    }                                                                         \
  } while (0)

  STAGE(0, 0);
  STAGE(1, 1);

  #pragma unroll 3
  for (int tau = 0; tau < 4 * NL; ++tau) {
    // own stage(tau) done (oldest 6); stage(tau+1)'s 6 stay in flight
    asm volatile("s_waitcnt vmcnt(6)" ::: "memory");
    __builtin_amdgcn_s_barrier();
    if ((tau & 3) == 0) LOADQ(tau >> 2);
    if (tau + 2 < 4 * NL) STAGE((tau + 2) % 3, tau + 2);
    const int cur = tau % 3;

    #pragma unroll
    for (int mbi = 0; mbi < 2; ++mbi) {
      const int mb = mbi ^ (wave & 1);   // wave-staggered phase order
      // ---- S^T via MX K=64: lane holds S[m = mb*32+(r&3)+8(r>>2)+4hi][n]
      f32x16 ss[2];
      ss[0] = (f32x16)0.f; ss[1] = (f32x16)0.f;
      const int row = mb * 32 + l31;
      const int R = row >> 1;
      __builtin_amdgcn_s_setprio(1);
      #pragma unroll
      for (int kk = 0; kk < 2; ++kk) {
        int p0 = (((row & 1) << 3) | (kk * 4 + hi * 2)) ^ (R & 15);
        uint4 ka = *(const uint4*)&ks[cur][R][p0 * 16];
        uint4 kb = *(const uint4*)&ks[cur][R][(p0 ^ 1) * 16];
        i32x8 kf = cat8(ka, kb);
        ss[0] = mxm(kf, qf[0][kk], ss[0]);
        ss[1] = mxm(kf, qf[1][kk], ss[1]);
      }
      __builtin_amdgcn_s_setprio(0);

      // ---- 2^S + cvt_pk + permlane32_swap -> PV A-frags
      bf16x8 paL[2][2];
      #pragma unroll
      for (int nb = 0; nb < 2; ++nb) {
        #pragma unroll
        for (int s = 0; s < 2; ++s) {
          uint w0 = pk2(vexp2(ss[nb][8 * s + 0]), vexp2(ss[nb][8 * s + 1]));
          uint w1 = pk2(vexp2(ss[nb][8 * s + 2]), vexp2(ss[nb][8 * s + 3]));
          uint w2 = pk2(vexp2(ss[nb][8 * s + 4]), vexp2(ss[nb][8 * s + 5]));
          uint w3 = pk2(vexp2(ss[nb][8 * s + 6]), vexp2(ss[nb][8 * s + 7]));
          plswap(w0, w2);
          plswap(w1, w3);
          uint4 ui = make_uint4(w0, w1, w2, w3);
          paL[nb][s] = *(bf16x8*)&ui;
        }
      }

      // ---- PV: oacc[nb][cb] += P x V (k-steps 2mb, 2mb+1) — bf16
      __builtin_amdgcn_s_setprio(1);
      #pragma unroll
      for (int cb = 0; cb < 4; ++cb) {
        const int c = cb * 32 + l31;
        const int r = c & 63;
        #pragma unroll
        for (int s = 0; s < 2; ++s) {
          int qs = ((c >> 6) << 3) | (4 * mb + 2 * s + hi);
          bf16x8 vf = *(const bf16x8*)&vs[cur][r][(qs ^ (r & 15)) * 8];
          oacc[0][cb] = __builtin_amdgcn_mfma_f32_32x32x16_bf16(paL[0][s], vf, oacc[0][cb], 0, 0, 0);
          oacc[1][cb] = __builtin_amdgcn_mfma_f32_32x32x16_bf16(paL[1][s], vf, oacc[1][cb], 0, 0, 0);
        }
      }
      __builtin_amdgcn_s_setprio(0);
    }
  }
#undef STAGE
#undef LOADQ

  if (PART) {
    ushort* pz = part + (size_t)(ms * BCNT + b) * NTOK * CCH;
    #pragma unroll
    for (int nb = 0; nb < 2; ++nb)
      #pragma unroll
      for (int cb = 0; cb < 4; ++cb)
        #pragma unroll
        for (int r = 0; r < 16; ++r) {
          int n = nbase + nb * 32 + (r & 3) + 8 * (r >> 2) + 4 * hi;
          pz[(size_t)n * CCH + cb * 32 + l31] = f2bf(oacc[nb][cb][r]);
        }
  } else {
    float* az = accG + (size_t)b * NTOK * CCH;
    #pragma unroll
    for (int nb = 0; nb < 2; ++nb)
      #pragma unroll
      for (int cb = 0; cb < 4; ++cb)
        #pragma unroll
        for (int r = 0; r < 16; ++r) {
          int n = nbase + nb * 32 + (r & 3) + 8 * (r >> 2) + 4 * hi;
          atomicAdd(&az[(size_t)n * CCH + cb * 32 + l31], oacc[nb][cb][r]);
        }
  }
}

// ---------------------------------------------------------------------------
// finalize (atomic path): out[b][c][n] = acc[b][n][c] + x[b][c][n]
// ---------------------------------------------------------------------------
__global__ __launch_bounds__(256) void finalize_kernel(
    const float* __restrict__ acc, const float* __restrict__ x,
    float* __restrict__ out)
{
  __shared__ float ts[64][65];
  const int t = threadIdx.x;
  const int ntile = blockIdx.x * 64, ctile = blockIdx.y * 64, b = blockIdx.z;
  const float* ab = acc + ((size_t)b * NTOK + ntile) * CCH + ctile;
  #pragma unroll
  for (int p = 0; p < 4; ++p) {
    int idx = p * 256 + t;
    int nn = idx >> 4, c4 = (idx & 15) * 4;
    float4 v = *(const float4*)(ab + (size_t)nn * CCH + c4);
    ts[nn][c4 + 0] = v.x; ts[nn][c4 + 1] = v.y;
    ts[nn][c4 + 2] = v.z; ts[nn][c4 + 3] = v.w;
  }
  __syncthreads();
  const size_t base = ((size_t)b * CCH + ctile) * NTOK + ntile;
  #pragma unroll
  for (int p = 0; p < 16; ++p) {
    int idx = p * 256 + t;
    int nn = idx & 63, cc = idx >> 6;
    size_t o = base + (size_t)cc * NTOK + nn;
    out[o] = ts[nn][cc] + x[o];
  }
}

// ---------------------------------------------------------------------------
// finalize (partial path): out[b][c][n] = sum_ms part[ms][b][n][c] + x
// ---------------------------------------------------------------------------
__global__ __launch_bounds__(256) void finalize_part_kernel(
    const ushort* __restrict__ part, const float* __restrict__ x,
    float* __restrict__ out)
{
  __shared__ float ts[64][65];
  const int t = threadIdx.x;
  const int ntile = blockIdx.x * 64, ctile = blockIdx.y * 64, b = blockIdx.z;
  #pragma unroll
  for (int p = 0; p < 4; ++p) {
    int idx = p * 256 + t;
    int nn = idx >> 4, c4 = (idx & 15) * 4;
    float s0 = 0.f, s1 = 0.f, s2 = 0.f, s3 = 0.f;
    const ushort* pp = part + ((size_t)b * NTOK + ntile + nn) * CCH + ctile + c4;
    #pragma unroll
    for (int msi = 0; msi < 16; ++msi) {
      uint2 u = *(const uint2*)(pp + (size_t)msi * BCNT * NTOK * CCH);
      s0 += __uint_as_float(u.x << 16);
      s1 += __uint_as_float(u.x & 0xFFFF0000u);
      s2 += __uint_as_float(u.y << 16);
      s3 += __uint_as_float(u.y & 0xFFFF0000u);
    }
    ts[nn][c4 + 0] = s0; ts[nn][c4 + 1] = s1;
    ts[nn][c4 + 2] = s2; ts[nn][c4 + 3] = s3;
  }
  __syncthreads();
  const size_t base = ((size_t)b * CCH + ctile) * NTOK + ntile;
  #pragma unroll
  for (int p = 0; p < 16; ++p) {
    int idx = p * 256 + t;
    int nn = idx & 63, cc = idx >> 6;
    size_t o = base + (size_t)cc * NTOK + nn;
    out[o] = ts[nn][cc] + x[o];
  }
}

// ---------------------------------------------------------------------------
extern "C" void kernel_launch(void* const* d_in, const int* in_sizes, int n_in,
                              void* d_out, int out_size, void* d_ws, size_t ws_size,
                              hipStream_t stream)
{
  const float* x  = (const float*)d_in[0];
  const float* W1 = (const float*)d_in[1];
  const float* b1 = (const float*)d_in[2];
  const float* W2 = (const float*)d_in[3];
  const float* b2 = (const float*)d_in[4];
  const float* Wg = (const float*)d_in[5];
  const float* bg = (const float*)d_in[6];
  float* out = (float*)d_out;

  const size_t PL = (size_t)BCNT * NTOK * CCH;   // 1,048,576 elements per z-pair slab
  const size_t DSZ = (size_t)BCNT * NTOK;        // 8192
  const size_t WBSZ = (size_t)3 * NLAY * CCH * CCH;

  // need(nb) = xT + nb*(vv + q8 + k8) + Wb + nb*D + acc [+ part]
  int nb = 1;
  for (int cand : {6, 3, 2}) {
    size_t need = PL * 2 + (size_t)cand * (PL * 2 + PL + PL) + WBSZ * 2
                + (size_t)cand * DSZ * 4 + PL * 4;
    if (ws_size >= need) { nb = cand; break; }
  }
  size_t need_base = PL * 2 + (size_t)nb * (PL * 2 + PL + PL) + WBSZ * 2
                   + (size_t)nb * DSZ * 4 + PL * 4;
  bool usePart = (nb == 6) && (ws_size >= need_base + 16 * PL * 2);

  char* p = (char*)d_ws;
  ushort* xT = (ushort*)p; p += PL * 2;
  ushort* vv = (ushort*)p; p += (size_t)nb * PL * 2;
  uchar*  q8 = (uchar*)p;  p += (size_t)nb * PL;
  uchar*  k8 = (uchar*)p;  p += (size_t)nb * PL;
  ushort* Wb = (ushort*)p; p += WBSZ * 2;
  float*  D  = (float*)p;  p += (size_t)nb * DSZ * 4;
  float*  acc= (float*)p;  p += PL * 4;
  ushort* part = (ushort*)p;   // 16 * PL bf16 when usePart

  if (!usePart) hipMemsetAsync(acc, 0, PL * 4, stream);
  transpose_kernel<<<dim3(NTOK / 64, CCH / 64, BCNT), 256, 0, stream>>>(x, xT);
  wcvt_kernel<<<dim3(96, 3), 256, 0, stream>>>(W1, W2, Wg, Wb);

  for (int l0 = 0; l0 < NLAY; l0 += nb) {
    const int LB = nb * BCNT;
    hipMemsetAsync(D, 0, (size_t)LB * NTOK * 4, stream);
    qkv_kernel<<<dim3(NTOK / 128, 3, LB), 256, 0, stream>>>(
        xT, Wb, b1, b2, bg, q8, k8, vv, l0);
    dsum_kernel<<<dim3(LB * 64), 256, 0, stream>>>(q8, k8, D);
    scalev_kernel<<<dim3(LB * 256), 256, 0, stream>>>(vv, D);
    const dim3 pvg(BCNT * 256);
    if (usePart) {
      pv_kernel<6, true><<<pvg, 256, 0, stream>>>(q8, k8, vv, acc, part);
    } else {
      switch (nb) {
        case 6: pv_kernel<6, false><<<pvg, 256, 0, stream>>>(q8, k8, vv, acc, part); break;
        case 3: pv_kernel<3, false><<<pvg, 256, 0, stream>>>(q8, k8, vv, acc, part); break;
        case 2: pv_kernel<2, false><<<pvg, 256, 0, stream>>>(q8, k8, vv, acc, part); break;
        default: pv_kernel<1, false><<<pvg, 256, 0, stream>>>(q8, k8, vv, acc, part); break;
      }
    }
  }
  if (usePart)
    finalize_part_kernel<<<dim3(NTOK / 64, CCH / 64, BCNT), 256, 0, stream>>>(part, x, out);
  else
    finalize_kernel<<<dim3(NTOK / 64, CCH / 64, BCNT), 256, 0, stream>>>(acc, x, out);
}